// Round 1
// baseline (580.318 us; speedup 1.0000x reference)
//
#include <hip/hip_runtime.h>

#define EPSF 1e-6f

// ================= fp32 NT GEMM: C[m][n] = sum_k A[m][k] * B[n][k] =========
#define TM 128
#define TN 128
#define TK 16

__device__ __forceinline__ void gemm_nt_tile(
    const float* __restrict__ A, const float* __restrict__ Bw,
    float* __restrict__ C, const int K, const int N,
    const int row0, const int col0, const bool relu)
{
  __shared__ float As[TK][TM + 4];
  __shared__ float Bs[TK][TN + 4];
  const int tid = threadIdx.x;
  const int tx = tid & 15;
  const int ty = tid >> 4;
  float acc[8][8];
#pragma unroll
  for (int i = 0; i < 8; ++i)
#pragma unroll
    for (int j = 0; j < 8; ++j) acc[i][j] = 0.f;

  for (int k0 = 0; k0 < K; k0 += TK) {
#pragma unroll
    for (int r = 0; r < 2; ++r) {
      const int idx = tid + (r << 8);          // 0..511
      const int m = idx >> 2;                  // 0..127
      const int kq = (idx & 3) << 2;           // 0,4,8,12
      const float4 av = *(const float4*)(A + (size_t)(row0 + m) * K + (k0 + kq));
      As[kq + 0][m] = av.x; As[kq + 1][m] = av.y;
      As[kq + 2][m] = av.z; As[kq + 3][m] = av.w;
      const float4 bv = *(const float4*)(Bw + (size_t)(col0 + m) * K + (k0 + kq));
      Bs[kq + 0][m] = bv.x; Bs[kq + 1][m] = bv.y;
      Bs[kq + 2][m] = bv.z; Bs[kq + 3][m] = bv.w;
    }
    __syncthreads();
#pragma unroll
    for (int k = 0; k < TK; ++k) {
      const float4 a0 = *(const float4*)&As[k][ty * 8];
      const float4 a1 = *(const float4*)&As[k][ty * 8 + 4];
      const float4 b0 = *(const float4*)&Bs[k][tx * 8];
      const float4 b1 = *(const float4*)&Bs[k][tx * 8 + 4];
      const float av[8] = {a0.x, a0.y, a0.z, a0.w, a1.x, a1.y, a1.z, a1.w};
      const float bv[8] = {b0.x, b0.y, b0.z, b0.w, b1.x, b1.y, b1.z, b1.w};
#pragma unroll
      for (int i = 0; i < 8; ++i)
#pragma unroll
        for (int j = 0; j < 8; ++j)
          acc[i][j] = fmaf(av[i], bv[j], acc[i][j]);
    }
    __syncthreads();
  }

#pragma unroll
  for (int i = 0; i < 8; ++i) {
    float* crow = C + (size_t)(row0 + ty * 8 + i) * N + (col0 + tx * 8);
#pragma unroll
    for (int j = 0; j < 8; j += 4) {
      float4 v;
      v.x = acc[i][j + 0]; v.y = acc[i][j + 1];
      v.z = acc[i][j + 2]; v.w = acc[i][j + 3];
      if (relu) {
        v.x = fmaxf(v.x, 0.f) + EPSF;
        v.y = fmaxf(v.y, 0.f) + EPSF;
        v.z = fmaxf(v.z, 0.f) + EPSF;
        v.w = fmaxf(v.w, 0.f) + EPSF;
      }
      *(float4*)(crow + j) = v;
    }
  }
}

__global__ __launch_bounds__(256) void qkv_gemm_kernel(
    const float* __restrict__ x,
    const float* __restrict__ Wq, const float* __restrict__ Wk,
    const float* __restrict__ Wv,
    float* __restrict__ q, float* __restrict__ k, float* __restrict__ v)
{
  const int brow = blockIdx.x;           // 0..31
  const int which = blockIdx.y >> 3;     // 0=q 1=k 2=v
  const int bcol = blockIdx.y & 7;       // 0..7
  const float* W = (which == 0) ? Wq : (which == 1) ? Wk : Wv;
  float* C = (which == 0) ? q : (which == 1) ? k : v;
  gemm_nt_tile(x, W, C, 1024, 1024, brow * TM, bcol * TN, which < 2);
}

__global__ __launch_bounds__(256) void out_gemm_kernel(
    const float* __restrict__ attn, const float* __restrict__ Wo,
    float* __restrict__ out)
{
  gemm_nt_tile(attn, Wo, out, 1024, 1024, blockIdx.x * TM, blockIdx.y * TN, false);
}

// ================= chunked linear attention =================================
// Layouts: q/k/v/attn are (b*s, 1024) row-major, head h occupies cols h*64..h*64+63.
// seq = b*16+h (32 sequences), 32 chunks of 64 positions each.
// kvsum: [seq][chunk][64*64] (d-major, KV[d][m]); ksum: [seq][chunk][64].

__global__ __launch_bounds__(256) void chunk_sums_kernel(
    const float* __restrict__ kbuf, const float* __restrict__ vbuf,
    float* __restrict__ kvsum, float* __restrict__ ksum)
{
  __shared__ float Ks[64][68];
  __shared__ float Vs[64][68];
  const int chunk = blockIdx.x;
  const int seq = blockIdx.y;
  const int b = seq >> 4, h = seq & 15;
  const int tid = threadIdx.x;
  const size_t base = ((size_t)b * 2048 + chunk * 64) * 1024 + h * 64;
#pragma unroll
  for (int r = 0; r < 4; ++r) {
    const int idx = tid + (r << 8);
    const int row = idx >> 4;
    const int cq = (idx & 15) << 2;
    *(float4*)&Ks[row][cq] = *(const float4*)(kbuf + base + (size_t)row * 1024 + cq);
    *(float4*)&Vs[row][cq] = *(const float4*)(vbuf + base + (size_t)row * 1024 + cq);
  }
  __syncthreads();
  const int d0 = (tid >> 4) << 2;
  const int m0 = (tid & 15) << 2;
  float a[4][4] = {{0.f}};
  for (int j = 0; j < 64; ++j) {
    const float4 k4 = *(const float4*)&Ks[j][d0];
    const float4 v4 = *(const float4*)&Vs[j][m0];
    const float ka[4] = {k4.x, k4.y, k4.z, k4.w};
    const float va[4] = {v4.x, v4.y, v4.z, v4.w};
#pragma unroll
    for (int aa = 0; aa < 4; ++aa)
#pragma unroll
      for (int cc = 0; cc < 4; ++cc)
        a[aa][cc] = fmaf(ka[aa], va[cc], a[aa][cc]);
  }
  const size_t kvbase = ((size_t)seq * 32 + chunk) << 12;
#pragma unroll
  for (int aa = 0; aa < 4; ++aa) {
    float4 v;
    v.x = a[aa][0]; v.y = a[aa][1]; v.z = a[aa][2]; v.w = a[aa][3];
    *(float4*)(kvsum + kvbase + (size_t)(d0 + aa) * 64 + m0) = v;
  }
  if (tid < 64) {
    float s = 0.f;
    for (int j = 0; j < 64; ++j) s += Ks[j][tid];
    ksum[((size_t)seq * 32 + chunk) * 64 + tid] = s;
  }
}

// in-place exclusive prefix scan over chunks, one block per sequence
__global__ __launch_bounds__(256) void scan_kernel(
    float* __restrict__ kvsum, float* __restrict__ ksum)
{
  const int seq = blockIdx.x;
  const int tid = threadIdx.x;
  const size_t base = (size_t)seq << 17;   // seq * 32 * 4096
#pragma unroll
  for (int r = 0; r < 16; ++r) {
    const int e = tid + (r << 8);
    float run = 0.f;
    for (int c = 0; c < 32; ++c) {
      const size_t idx = base + ((size_t)c << 12) + e;
      const float t = kvsum[idx];
      kvsum[idx] = run;
      run += t;
    }
  }
  if (tid < 64) {
    const size_t kb = (size_t)seq * 32 * 64;
    float run = 0.f;
    for (int c = 0; c < 32; ++c) {
      const float t = ksum[kb + c * 64 + tid];
      ksum[kb + c * 64 + tid] = run;
      run += t;
    }
  }
}

__global__ __launch_bounds__(256) void attn_chunk_kernel(
    const float* __restrict__ qbuf, const float* __restrict__ kbuf,
    const float* __restrict__ vbuf, const float* __restrict__ kvsum,
    const float* __restrict__ ksum, float* __restrict__ attn)
{
  __shared__ float Qt[64][68];   // Qt[d][i]
  __shared__ float Kt[64][68];   // Kt[d][j], later reused as KVp[d][m]
  __shared__ float Vs[64][68];   // Vs[j][m]
  __shared__ float St[64][68];   // St[j][i] = S[i][j] = q_i . k_j
  __shared__ float ksp[64];
  __shared__ float zinv[64];
  const int chunk = blockIdx.x;
  const int seq = blockIdx.y;
  const int b = seq >> 4, h = seq & 15;
  const int tid = threadIdx.x;
  const size_t base = ((size_t)b * 2048 + chunk * 64) * 1024 + h * 64;
#pragma unroll
  for (int r = 0; r < 4; ++r) {
    const int idx = tid + (r << 8);
    const int row = idx >> 4;
    const int cq = (idx & 15) << 2;
    const float4 q4 = *(const float4*)(qbuf + base + (size_t)row * 1024 + cq);
    Qt[cq + 0][row] = q4.x; Qt[cq + 1][row] = q4.y;
    Qt[cq + 2][row] = q4.z; Qt[cq + 3][row] = q4.w;
    const float4 k4 = *(const float4*)(kbuf + base + (size_t)row * 1024 + cq);
    Kt[cq + 0][row] = k4.x; Kt[cq + 1][row] = k4.y;
    Kt[cq + 2][row] = k4.z; Kt[cq + 3][row] = k4.w;
    *(float4*)&Vs[row][cq] = *(const float4*)(vbuf + base + (size_t)row * 1024 + cq);
  }
  if (tid < 64) ksp[tid] = ksum[((size_t)seq * 32 + chunk) * 64 + tid];
  __syncthreads();

  const int i0 = (tid >> 4) << 2;   // S row block / output row block
  const int j0 = (tid & 15) << 2;   // S col block / output col block (m)

  // S = Q K^T (4x4 per thread), stored transposed: St[j][i]
  {
    float s[4][4] = {{0.f}};
    for (int d = 0; d < 64; ++d) {
      const float4 q4 = *(const float4*)&Qt[d][i0];
      const float4 k4 = *(const float4*)&Kt[d][j0];
      const float qa[4] = {q4.x, q4.y, q4.z, q4.w};
      const float kb2[4] = {k4.x, k4.y, k4.z, k4.w};
#pragma unroll
      for (int aa = 0; aa < 4; ++aa)
#pragma unroll
        for (int cc = 0; cc < 4; ++cc)
          s[aa][cc] = fmaf(qa[aa], kb2[cc], s[aa][cc]);
    }
#pragma unroll
    for (int cc = 0; cc < 4; ++cc) {
      float4 v;
      v.x = s[0][cc]; v.y = s[1][cc]; v.z = s[2][cc]; v.w = s[3][cc];
      *(float4*)&St[j0 + cc][i0] = v;
    }
  }
  __syncthreads();   // St complete; Kt free to overwrite

  // load KV prefix into Kt; compute z on first 64 threads
  const size_t kvbase = ((size_t)seq * 32 + chunk) << 12;
#pragma unroll
  for (int r = 0; r < 4; ++r) {
    const int idx = tid + (r << 8);
    const int row = idx >> 4;       // d
    const int cq = (idx & 15) << 2; // m
    *(float4*)&Kt[row][cq] = *(const float4*)(kvsum + kvbase + (size_t)row * 64 + cq);
  }
  if (tid < 64) {
    const int i = tid;
    float dsum = 0.f;
    for (int d = 0; d < 64; ++d) dsum = fmaf(Qt[d][i], ksp[d], dsum);
    float ssum = 0.f;
    for (int j = 0; j <= i; ++j) ssum += St[j][i];
    zinv[i] = 1.f / (dsum + ssum + EPSF);
  }
  __syncthreads();

  float o[4][4] = {{0.f}};
  // inter-chunk: Q @ KVprefix
  for (int d = 0; d < 64; ++d) {
    const float4 q4 = *(const float4*)&Qt[d][i0];
    const float4 p4 = *(const float4*)&Kt[d][j0];
    const float qa[4] = {q4.x, q4.y, q4.z, q4.w};
    const float pa[4] = {p4.x, p4.y, p4.z, p4.w};
#pragma unroll
    for (int aa = 0; aa < 4; ++aa)
#pragma unroll
      for (int cc = 0; cc < 4; ++cc)
        o[aa][cc] = fmaf(qa[aa], pa[cc], o[aa][cc]);
  }
  // intra-chunk, full rows j < i0
  for (int j = 0; j < i0; ++j) {
    const float4 s4 = *(const float4*)&St[j][i0];
    const float4 v4 = *(const float4*)&Vs[j][j0];
    const float sa[4] = {s4.x, s4.y, s4.z, s4.w};
    const float va[4] = {v4.x, v4.y, v4.z, v4.w};
#pragma unroll
    for (int aa = 0; aa < 4; ++aa)
#pragma unroll
      for (int cc = 0; cc < 4; ++cc)
        o[aa][cc] = fmaf(sa[aa], va[cc], o[aa][cc]);
  }
  // triangular tail j = i0..i0+3: row i0+aa includes j iff jt <= aa
#pragma unroll
  for (int jt = 0; jt < 4; ++jt) {
    const int j = i0 + jt;
    const float4 s4 = *(const float4*)&St[j][i0];
    const float4 v4 = *(const float4*)&Vs[j][j0];
    const float sa[4] = {s4.x, s4.y, s4.z, s4.w};
    const float va[4] = {v4.x, v4.y, v4.z, v4.w};
#pragma unroll
    for (int aa = jt; aa < 4; ++aa)
#pragma unroll
      for (int cc = 0; cc < 4; ++cc)
        o[aa][cc] = fmaf(sa[aa], va[cc], o[aa][cc]);
  }
  // scale by 1/z and write
#pragma unroll
  for (int aa = 0; aa < 4; ++aa) {
    const float z = zinv[i0 + aa];
    float4 v;
    v.x = o[aa][0] * z; v.y = o[aa][1] * z;
    v.z = o[aa][2] * z; v.w = o[aa][3] * z;
    *(float4*)(attn + base + (size_t)(i0 + aa) * 1024 + j0) = v;
  }
}

// ================= launch ==================================================
extern "C" void kernel_launch(void* const* d_in, const int* in_sizes, int n_in,
                              void* d_out, int out_size, void* d_ws, size_t ws_size,
                              hipStream_t stream)
{
  (void)in_sizes; (void)n_in; (void)out_size; (void)ws_size;
  const float* x  = (const float*)d_in[0];
  const float* Wq = (const float*)d_in[1];
  const float* Wk = (const float*)d_in[2];
  const float* Wv = (const float*)d_in[3];
  const float* Wo = (const float*)d_in[4];
  float* out = (float*)d_out;

  const size_t NM = (size_t)4096 * 1024;
  float* wsf = (float*)d_ws;
  float* qb  = wsf;
  float* kb  = qb + NM;
  float* vb  = kb + NM;
  float* at  = vb + NM;
  float* kvs = at + NM;          // 32*32*4096 == NM floats
  float* ksm = kvs + NM;         // 32*32*64 = 65536 floats

  qkv_gemm_kernel<<<dim3(32, 24), 256, 0, stream>>>(x, Wq, Wk, Wv, qb, kb, vb);
  chunk_sums_kernel<<<dim3(32, 32), 256, 0, stream>>>(kb, vb, kvs, ksm);
  scan_kernel<<<32, 256, 0, stream>>>(kvs, ksm);
  attn_chunk_kernel<<<dim3(32, 32), 256, 0, stream>>>(qb, kb, vb, kvs, ksm, at);
  out_gemm_kernel<<<dim3(32, 8), 256, 0, stream>>>(at, Wo, out);
}

// Round 2
// 203.981 us; speedup vs baseline: 2.8450x; 2.8450x over previous
//
#include <hip/hip_runtime.h>

#define EPSF 1e-6f

typedef short bf16x8_t __attribute__((ext_vector_type(8)));
typedef float f32x4_t __attribute__((ext_vector_type(4)));

__device__ __forceinline__ ushort f2bf(float f) {
  union { float f; uint32_t u; } c; c.f = f;
  return (ushort)((c.u + 0x7FFFu + ((c.u >> 16) & 1u)) >> 16);
}

// ============ f32 -> bf16 conversion for x, Wq, Wk, Wv, Wo ==================
__global__ __launch_bounds__(256) void cvt5_kernel(
    const float4* __restrict__ x, const float4* __restrict__ wq,
    const float4* __restrict__ wk, const float4* __restrict__ wv,
    const float4* __restrict__ wo,
    ushort4* __restrict__ xb, ushort4* __restrict__ wqb,
    ushort4* __restrict__ wkb, ushort4* __restrict__ wvb,
    ushort4* __restrict__ wob)
{
  const int i = blockIdx.x * 256 + threadIdx.x;   // float4 index, 0..2M-1
  const float4* src; ushort4* dst; int off;
  if (i < (1 << 20)) { src = x; dst = xb; off = i; }
  else {
    const int j = i - (1 << 20);
    const int r = j >> 18;
    off = j & ((1 << 18) - 1);
    src = (r == 0) ? wq : (r == 1) ? wk : (r == 2) ? wv : wo;
    dst = (r == 0) ? wqb : (r == 1) ? wkb : (r == 2) ? wvb : wob;
  }
  const float4 v = src[off];
  ushort4 o;
  o.x = f2bf(v.x); o.y = f2bf(v.y); o.z = f2bf(v.z); o.w = f2bf(v.w);
  dst[off] = o;
}

// ============ bf16 MFMA NT GEMM: C[m][n] = sum_k A[m][k]*B[n][k] ============
// A: M x K bf16 row-major; B: N x K bf16 row-major (i.e. x @ W.T layout).
// 128x128 tile, BK=32, 4 waves (2x2), 4x4 fragments of 16x16x32 per wave.
template<int RELU, int OUT_BF16>
__device__ __forceinline__ void gemm_bt_mfma(
    const ushort* __restrict__ A, const ushort* __restrict__ B,
    void* __restrict__ C, const int K, const int N,
    const int row0, const int col0)
{
  __shared__ __align__(16) ushort As[128 * 32];
  __shared__ __align__(16) ushort Bs[128 * 32];
  const int tid = threadIdx.x;
  const int lane = tid & 63;
  const int wv = tid >> 6;          // 0..3
  const int wr = (wv >> 1) * 64;    // wave row offset
  const int wc = (wv & 1) * 64;     // wave col offset

  f32x4_t acc[4][4];
#pragma unroll
  for (int m = 0; m < 4; ++m)
#pragma unroll
    for (int n = 0; n < 4; ++n) acc[m][n] = (f32x4_t){0.f, 0.f, 0.f, 0.f};

  const int fr = lane & 15;
  const int kh = (lane >> 4) * 8;

  for (int k0 = 0; k0 < K; k0 += 32) {
    __syncthreads();   // previous iteration's ds_reads done before overwrite
#pragma unroll
    for (int issue = 0; issue < 2; ++issue) {
      const int chunk = wv * 64 + lane + issue * 256;   // 0..511
      const int row = chunk >> 2;                       // 0..127
      const int kp = chunk & 3;                         // k-part * 8
      const ushort* gsrcA = A + (size_t)(row0 + row) * K + k0 + kp * 8;
      const ushort* gsrcB = B + (size_t)(col0 + row) * K + k0 + kp * 8;
      ushort* ldstA = As + (size_t)(wv * 64 + issue * 256) * 8;  // wave-uniform
      ushort* ldstB = Bs + (size_t)(wv * 64 + issue * 256) * 8;
      __builtin_amdgcn_global_load_lds(
          (const __attribute__((address_space(1))) void*)gsrcA,
          (__attribute__((address_space(3))) void*)ldstA, 16, 0, 0);
      __builtin_amdgcn_global_load_lds(
          (const __attribute__((address_space(1))) void*)gsrcB,
          (__attribute__((address_space(3))) void*)ldstB, 16, 0, 0);
    }
    __syncthreads();   // drains vmcnt -> LDS tiles ready

    bf16x8_t af[4], bfr[4];
#pragma unroll
    for (int m = 0; m < 4; ++m)
      af[m] = *(const bf16x8_t*)&As[(size_t)(wr + m * 16 + fr) * 32 + kh];
#pragma unroll
    for (int n = 0; n < 4; ++n)
      bfr[n] = *(const bf16x8_t*)&Bs[(size_t)(wc + n * 16 + fr) * 32 + kh];
#pragma unroll
    for (int m = 0; m < 4; ++m)
#pragma unroll
      for (int n = 0; n < 4; ++n)
        acc[m][n] = __builtin_amdgcn_mfma_f32_16x16x32_bf16(
            af[m], bfr[n], acc[m][n], 0, 0, 0);
  }

  // epilogue: within fragment, col = lane&15, row = (lane>>4)*4 + r
  const int rq = (lane >> 4) * 4;
#pragma unroll
  for (int m = 0; m < 4; ++m) {
#pragma unroll
    for (int r = 0; r < 4; ++r) {
      const size_t grow = (size_t)(row0 + wr + m * 16 + rq + r);
#pragma unroll
      for (int n = 0; n < 4; ++n) {
        float val = acc[m][n][r];
        if (RELU) val = fmaxf(val, 0.f) + EPSF;
        const size_t gcol = (size_t)(col0 + wc + n * 16 + fr);
        if (OUT_BF16) ((ushort*)C)[grow * N + gcol] = f2bf(val);
        else          ((float*)C)[grow * N + gcol] = val;
      }
    }
  }
}

__global__ __launch_bounds__(256) void qkv_gemm_kernel(
    const ushort* __restrict__ xb,
    const ushort* __restrict__ wqb, const ushort* __restrict__ wkb,
    const ushort* __restrict__ wvb,
    float* __restrict__ q, float* __restrict__ k, float* __restrict__ v)
{
  const int which = blockIdx.y >> 3;
  const int bcol = blockIdx.y & 7;
  const ushort* B = (which == 0) ? wqb : (which == 1) ? wkb : wvb;
  float* C = (which == 0) ? q : (which == 1) ? k : v;
  if (which < 2)
    gemm_bt_mfma<1, 0>(xb, B, C, 1024, 1024, blockIdx.x * 128, bcol * 128);
  else
    gemm_bt_mfma<0, 0>(xb, B, C, 1024, 1024, blockIdx.x * 128, bcol * 128);
}

__global__ __launch_bounds__(256) void out_gemm_kernel(
    const ushort* __restrict__ at, const ushort* __restrict__ wob,
    float* __restrict__ out)
{
  gemm_bt_mfma<0, 0>(at, wob, out, 1024, 1024, blockIdx.x * 128, blockIdx.y * 128);
}

// ================= chunked linear attention (fp32 vector) ===================
// q/k/v: (b*s, 1024) fp32 row-major, head h at cols h*64..h*64+63.
// seq = b*16+h (32 sequences), 32 chunks of 64 positions.
// kvsum: [seq][chunk][64*64] (KV[d][m]); ksum: [seq][chunk][64].

__global__ __launch_bounds__(256) void chunk_sums_kernel(
    const float* __restrict__ kbuf, const float* __restrict__ vbuf,
    float* __restrict__ kvsum, float* __restrict__ ksum)
{
  __shared__ float Ks[64][68];
  __shared__ float Vs[64][68];
  const int chunk = blockIdx.x;
  const int seq = blockIdx.y;
  const int b = seq >> 4, h = seq & 15;
  const int tid = threadIdx.x;
  const size_t base = ((size_t)b * 2048 + chunk * 64) * 1024 + h * 64;
#pragma unroll
  for (int r = 0; r < 4; ++r) {
    const int idx = tid + (r << 8);
    const int row = idx >> 4;
    const int cq = (idx & 15) << 2;
    *(float4*)&Ks[row][cq] = *(const float4*)(kbuf + base + (size_t)row * 1024 + cq);
    *(float4*)&Vs[row][cq] = *(const float4*)(vbuf + base + (size_t)row * 1024 + cq);
  }
  __syncthreads();
  const int d0 = (tid >> 4) << 2;
  const int m0 = (tid & 15) << 2;
  float a[4][4] = {{0.f}};
  for (int j = 0; j < 64; ++j) {
    const float4 k4 = *(const float4*)&Ks[j][d0];
    const float4 v4 = *(const float4*)&Vs[j][m0];
    const float ka[4] = {k4.x, k4.y, k4.z, k4.w};
    const float va[4] = {v4.x, v4.y, v4.z, v4.w};
#pragma unroll
    for (int aa = 0; aa < 4; ++aa)
#pragma unroll
      for (int cc = 0; cc < 4; ++cc)
        a[aa][cc] = fmaf(ka[aa], va[cc], a[aa][cc]);
  }
  const size_t kvbase = ((size_t)seq * 32 + chunk) << 12;
#pragma unroll
  for (int aa = 0; aa < 4; ++aa) {
    float4 v;
    v.x = a[aa][0]; v.y = a[aa][1]; v.z = a[aa][2]; v.w = a[aa][3];
    *(float4*)(kvsum + kvbase + (size_t)(d0 + aa) * 64 + m0) = v;
  }
  if (tid < 64) {
    float s = 0.f;
    for (int j = 0; j < 64; ++j) s += Ks[j][tid];
    ksum[((size_t)seq * 32 + chunk) * 64 + tid] = s;
  }
}

// exclusive prefix scan over chunks; grid = 32 seq * 16 slices
__global__ __launch_bounds__(256) void scan_kernel(
    float* __restrict__ kvsum, float* __restrict__ ksum)
{
  const int slice = blockIdx.x & 15;
  const int seq = blockIdx.x >> 4;
  const int e = slice * 256 + threadIdx.x;   // 0..4095
  const size_t base = ((size_t)seq << 17) + e;
  float run = 0.f;
  for (int c = 0; c < 32; ++c) {
    const size_t idx = base + ((size_t)c << 12);
    const float t = kvsum[idx];
    kvsum[idx] = run;
    run += t;
  }
  if (slice == 0 && threadIdx.x < 64) {
    const size_t kb = (size_t)seq * 2048 + threadIdx.x;
    float run2 = 0.f;
    for (int c = 0; c < 32; ++c) {
      const float t = ksum[kb + (size_t)c * 64];
      ksum[kb + (size_t)c * 64] = run2;
      run2 += t;
    }
  }
}

__global__ __launch_bounds__(256) void attn_chunk_kernel(
    const float* __restrict__ qbuf, const float* __restrict__ kbuf,
    const float* __restrict__ vbuf, const float* __restrict__ kvsum,
    const float* __restrict__ ksum, ushort* __restrict__ attn)
{
  __shared__ float Qt[64][68];   // Qt[d][i]
  __shared__ float Kt[64][68];   // Kt[d][j], later reused as KVp[d][m]
  __shared__ float Vs[64][68];   // Vs[j][m]
  __shared__ float St[64][68];   // St[j][i] = S[i][j] = q_i . k_j
  __shared__ float ksp[64];
  __shared__ float zinv[64];
  const int chunk = blockIdx.x;
  const int seq = blockIdx.y;
  const int b = seq >> 4, h = seq & 15;
  const int tid = threadIdx.x;
  const size_t base = ((size_t)b * 2048 + chunk * 64) * 1024 + h * 64;
#pragma unroll
  for (int r = 0; r < 4; ++r) {
    const int idx = tid + (r << 8);
    const int row = idx >> 4;
    const int cq = (idx & 15) << 2;
    const float4 q4 = *(const float4*)(qbuf + base + (size_t)row * 1024 + cq);
    Qt[cq + 0][row] = q4.x; Qt[cq + 1][row] = q4.y;
    Qt[cq + 2][row] = q4.z; Qt[cq + 3][row] = q4.w;
    const float4 k4 = *(const float4*)(kbuf + base + (size_t)row * 1024 + cq);
    Kt[cq + 0][row] = k4.x; Kt[cq + 1][row] = k4.y;
    Kt[cq + 2][row] = k4.z; Kt[cq + 3][row] = k4.w;
    *(float4*)&Vs[row][cq] = *(const float4*)(vbuf + base + (size_t)row * 1024 + cq);
  }
  if (tid < 64) ksp[tid] = ksum[((size_t)seq * 32 + chunk) * 64 + tid];
  __syncthreads();

  const int i0 = (tid >> 4) << 2;
  const int j0 = (tid & 15) << 2;

  {
    float s[4][4] = {{0.f}};
    for (int d = 0; d < 64; ++d) {
      const float4 q4 = *(const float4*)&Qt[d][i0];
      const float4 k4 = *(const float4*)&Kt[d][j0];
      const float qa[4] = {q4.x, q4.y, q4.z, q4.w};
      const float kb2[4] = {k4.x, k4.y, k4.z, k4.w};
#pragma unroll
      for (int aa = 0; aa < 4; ++aa)
#pragma unroll
        for (int cc = 0; cc < 4; ++cc)
          s[aa][cc] = fmaf(qa[aa], kb2[cc], s[aa][cc]);
    }
#pragma unroll
    for (int cc = 0; cc < 4; ++cc) {
      float4 v;
      v.x = s[0][cc]; v.y = s[1][cc]; v.z = s[2][cc]; v.w = s[3][cc];
      *(float4*)&St[j0 + cc][i0] = v;
    }
  }
  __syncthreads();

  const size_t kvbase = ((size_t)seq * 32 + chunk) << 12;
#pragma unroll
  for (int r = 0; r < 4; ++r) {
    const int idx = tid + (r << 8);
    const int row = idx >> 4;
    const int cq = (idx & 15) << 2;
    *(float4*)&Kt[row][cq] = *(const float4*)(kvsum + kvbase + (size_t)row * 64 + cq);
  }
  if (tid < 64) {
    const int i = tid;
    float dsum = 0.f;
    for (int d = 0; d < 64; ++d) dsum = fmaf(Qt[d][i], ksp[d], dsum);
    float ssum = 0.f;
    for (int j = 0; j <= i; ++j) ssum += St[j][i];
    zinv[i] = 1.f / (dsum + ssum + EPSF);
  }
  __syncthreads();

  float o[4][4] = {{0.f}};
  for (int d = 0; d < 64; ++d) {
    const float4 q4 = *(const float4*)&Qt[d][i0];
    const float4 p4 = *(const float4*)&Kt[d][j0];
    const float qa[4] = {q4.x, q4.y, q4.z, q4.w};
    const float pa[4] = {p4.x, p4.y, p4.z, p4.w};
#pragma unroll
    for (int aa = 0; aa < 4; ++aa)
#pragma unroll
      for (int cc = 0; cc < 4; ++cc)
        o[aa][cc] = fmaf(qa[aa], pa[cc], o[aa][cc]);
  }
  for (int j = 0; j < i0; ++j) {
    const float4 s4 = *(const float4*)&St[j][i0];
    const float4 v4 = *(const float4*)&Vs[j][j0];
    const float sa[4] = {s4.x, s4.y, s4.z, s4.w};
    const float va[4] = {v4.x, v4.y, v4.z, v4.w};
#pragma unroll
    for (int aa = 0; aa < 4; ++aa)
#pragma unroll
      for (int cc = 0; cc < 4; ++cc)
        o[aa][cc] = fmaf(sa[aa], va[cc], o[aa][cc]);
  }
#pragma unroll
  for (int jt = 0; jt < 4; ++jt) {
    const int j = i0 + jt;
    const float4 s4 = *(const float4*)&St[j][i0];
    const float4 v4 = *(const float4*)&Vs[j][j0];
    const float sa[4] = {s4.x, s4.y, s4.z, s4.w};
    const float va[4] = {v4.x, v4.y, v4.z, v4.w};
#pragma unroll
    for (int aa = jt; aa < 4; ++aa)
#pragma unroll
      for (int cc = 0; cc < 4; ++cc)
        o[aa][cc] = fmaf(sa[aa], va[cc], o[aa][cc]);
  }
#pragma unroll
  for (int aa = 0; aa < 4; ++aa) {
    const float z = zinv[i0 + aa];
    ushort4 ov;
    ov.x = f2bf(o[aa][0] * z); ov.y = f2bf(o[aa][1] * z);
    ov.z = f2bf(o[aa][2] * z); ov.w = f2bf(o[aa][3] * z);
    *(ushort4*)(attn + base + (size_t)(i0 + aa) * 1024 + j0) = ov;
  }
}

// ================= launch ==================================================
extern "C" void kernel_launch(void* const* d_in, const int* in_sizes, int n_in,
                              void* d_out, int out_size, void* d_ws, size_t ws_size,
                              hipStream_t stream)
{
  (void)in_sizes; (void)n_in; (void)out_size; (void)ws_size;
  const float* x  = (const float*)d_in[0];
  const float* Wq = (const float*)d_in[1];
  const float* Wk = (const float*)d_in[2];
  const float* Wv = (const float*)d_in[3];
  const float* Wo = (const float*)d_in[4];
  float* out = (float*)d_out;

  const size_t NM = (size_t)4096 * 1024;
  float* wsf = (float*)d_ws;
  float* qb  = wsf;                 // fp32, NM
  float* kb  = qb + NM;
  float* vb  = kb + NM;
  float* ksm = vb + NM;             // 65536 floats
  ushort* xb  = (ushort*)(ksm + 65536);   // bf16, NM
  ushort* wqb = xb + NM;            // bf16, 1M each
  ushort* wkb = wqb + (1 << 20);
  ushort* wvb = wkb + (1 << 20);
  ushort* wob = wvb + (1 << 20);
  ushort* at  = wob + (1 << 20);    // bf16, NM
  float* kvs = (float*)d_out;       // reuse d_out as kvsum scratch (NM floats)

  cvt5_kernel<<<8192, 256, 0, stream>>>(
      (const float4*)x, (const float4*)Wq, (const float4*)Wk,
      (const float4*)Wv, (const float4*)Wo,
      (ushort4*)xb, (ushort4*)wqb, (ushort4*)wkb, (ushort4*)wvb, (ushort4*)wob);
  qkv_gemm_kernel<<<dim3(32, 24), 256, 0, stream>>>(xb, wqb, wkb, wvb, qb, kb, vb);
  chunk_sums_kernel<<<dim3(32, 32), 256, 0, stream>>>(kb, vb, kvs, ksm);
  scan_kernel<<<512, 256, 0, stream>>>(kvs, ksm);
  attn_chunk_kernel<<<dim3(32, 32), 256, 0, stream>>>(qb, kb, vb, kvs, ksm, at);
  out_gemm_kernel<<<dim3(32, 8), 256, 0, stream>>>(at, wob, out);
}

// Round 3
// 168.048 us; speedup vs baseline: 3.4533x; 1.2138x over previous
//
#include <hip/hip_runtime.h>

#define EPSF 1e-6f

typedef short bf16x8_t __attribute__((ext_vector_type(8)));
typedef float f32x4_t __attribute__((ext_vector_type(4)));

__device__ __forceinline__ ushort f2bf(float f) {
  union { float f; uint32_t u; } c; c.f = f;
  return (ushort)((c.u + 0x7FFFu + ((c.u >> 16) & 1u)) >> 16);
}
__device__ __forceinline__ float bf2f(ushort u) {
  union { uint32_t u; float f; } c; c.u = ((uint32_t)u) << 16;
  return c.f;
}

// swizzled byte offset into a 64x64 bf16 LDS tile (row stride 128 B)
#define SWB(row, kbyte) (((row) << 7) + ((kbyte) ^ (((row) & 7) << 4)))

// ============ f32 -> bf16 conversion for x, Wq, Wk, Wv, Wo ==================
__global__ __launch_bounds__(256) void cvt5_kernel(
    const float4* __restrict__ x, const float4* __restrict__ wq,
    const float4* __restrict__ wk, const float4* __restrict__ wv,
    const float4* __restrict__ wo,
    ushort4* __restrict__ xb, ushort4* __restrict__ wqb,
    ushort4* __restrict__ wkb, ushort4* __restrict__ wvb,
    ushort4* __restrict__ wob)
{
  const int i = blockIdx.x * 256 + threadIdx.x;   // float4 index, 0..2M-1
  const float4* src; ushort4* dst; int off;
  if (i < (1 << 20)) { src = x; dst = xb; off = i; }
  else {
    const int j = i - (1 << 20);
    const int r = j >> 18;
    off = j & ((1 << 18) - 1);
    src = (r == 0) ? wq : (r == 1) ? wk : (r == 2) ? wv : wo;
    dst = (r == 0) ? wqb : (r == 1) ? wkb : (r == 2) ? wvb : wob;
  }
  const float4 v = src[off];
  ushort4 o;
  o.x = f2bf(v.x); o.y = f2bf(v.y); o.z = f2bf(v.z); o.w = f2bf(v.w);
  dst[off] = o;
}

// ============ bf16 MFMA NT GEMM: C[m][n] = sum_k A[m][k]*B[n][k] ============
// 128x128 tile, BK=32, 4 waves (2x2), 4x4 fragments of 16x16x32 per wave.
template<int RELU, int OUT_BF16>
__device__ __forceinline__ void gemm_bt_mfma(
    const ushort* __restrict__ A, const ushort* __restrict__ B,
    void* __restrict__ C, const int K, const int N,
    const int row0, const int col0)
{
  __shared__ __align__(16) ushort As[128 * 32];
  __shared__ __align__(16) ushort Bs[128 * 32];
  const int tid = threadIdx.x;
  const int lane = tid & 63;
  const int wv = tid >> 6;
  const int wr = (wv >> 1) * 64;
  const int wc = (wv & 1) * 64;

  f32x4_t acc[4][4];
#pragma unroll
  for (int m = 0; m < 4; ++m)
#pragma unroll
    for (int n = 0; n < 4; ++n) acc[m][n] = (f32x4_t){0.f, 0.f, 0.f, 0.f};

  const int fr = lane & 15;
  const int kh = (lane >> 4) * 8;

  for (int k0 = 0; k0 < K; k0 += 32) {
    __syncthreads();
#pragma unroll
    for (int issue = 0; issue < 2; ++issue) {
      const int chunk = wv * 64 + lane + issue * 256;
      const int row = chunk >> 2;
      const int kp = chunk & 3;
      const ushort* gsrcA = A + (size_t)(row0 + row) * K + k0 + kp * 8;
      const ushort* gsrcB = B + (size_t)(col0 + row) * K + k0 + kp * 8;
      ushort* ldstA = As + (size_t)(wv * 64 + issue * 256) * 8;
      ushort* ldstB = Bs + (size_t)(wv * 64 + issue * 256) * 8;
      __builtin_amdgcn_global_load_lds(
          (const __attribute__((address_space(1))) void*)gsrcA,
          (__attribute__((address_space(3))) void*)ldstA, 16, 0, 0);
      __builtin_amdgcn_global_load_lds(
          (const __attribute__((address_space(1))) void*)gsrcB,
          (__attribute__((address_space(3))) void*)ldstB, 16, 0, 0);
    }
    __syncthreads();

    bf16x8_t af[4], bfr[4];
#pragma unroll
    for (int m = 0; m < 4; ++m)
      af[m] = *(const bf16x8_t*)&As[(size_t)(wr + m * 16 + fr) * 32 + kh];
#pragma unroll
    for (int n = 0; n < 4; ++n)
      bfr[n] = *(const bf16x8_t*)&Bs[(size_t)(wc + n * 16 + fr) * 32 + kh];
#pragma unroll
    for (int m = 0; m < 4; ++m)
#pragma unroll
      for (int n = 0; n < 4; ++n)
        acc[m][n] = __builtin_amdgcn_mfma_f32_16x16x32_bf16(
            af[m], bfr[n], acc[m][n], 0, 0, 0);
  }

  const int rq = (lane >> 4) * 4;
#pragma unroll
  for (int m = 0; m < 4; ++m) {
#pragma unroll
    for (int r = 0; r < 4; ++r) {
      const size_t grow = (size_t)(row0 + wr + m * 16 + rq + r);
#pragma unroll
      for (int n = 0; n < 4; ++n) {
        float val = acc[m][n][r];
        if (RELU) val = fmaxf(val, 0.f) + EPSF;
        const size_t gcol = (size_t)(col0 + wc + n * 16 + fr);
        if (OUT_BF16) ((ushort*)C)[grow * N + gcol] = f2bf(val);
        else          ((float*)C)[grow * N + gcol] = val;
      }
    }
  }
}

__global__ __launch_bounds__(256) void qkv_gemm_kernel(
    const ushort* __restrict__ xb,
    const ushort* __restrict__ wqb, const ushort* __restrict__ wkb,
    const ushort* __restrict__ wvb,
    ushort* __restrict__ q, ushort* __restrict__ k, ushort* __restrict__ v)
{
  const int which = blockIdx.y >> 3;
  const int bcol = blockIdx.y & 7;
  const ushort* B = (which == 0) ? wqb : (which == 1) ? wkb : wvb;
  ushort* C = (which == 0) ? q : (which == 1) ? k : v;
  if (which < 2)
    gemm_bt_mfma<1, 1>(xb, B, C, 1024, 1024, blockIdx.x * 128, bcol * 128);
  else
    gemm_bt_mfma<0, 1>(xb, B, C, 1024, 1024, blockIdx.x * 128, bcol * 128);
}

__global__ __launch_bounds__(256) void out_gemm_kernel(
    const ushort* __restrict__ at, const ushort* __restrict__ wob,
    float* __restrict__ out)
{
  gemm_bt_mfma<0, 0>(at, wob, out, 1024, 1024, blockIdx.x * 128, blockIdx.y * 128);
}

// ================= chunked linear attention (bf16 MFMA) =====================
// q/k/v: (b*s, 1024) bf16 row-major, head h at cols h*64..h*64+63.
// seq = b*16+h (32 sequences), 32 chunks of 64 positions.
// kvsum: [seq][chunk][m][d] fp32 (KV^T); ksum: [seq][chunk][d] fp32.

// KVT[m][d] = sum_j V[j][m] * K[j][d] per chunk, via MFMA with LDS-transposed
// Kt[d][j], Vt[m][j].
__global__ __launch_bounds__(256) void chunk_sums_kernel(
    const ushort* __restrict__ kbuf, const ushort* __restrict__ vbuf,
    float* __restrict__ kvsum, float* __restrict__ ksum)
{
  __shared__ __align__(16) ushort Kt[64 * 64];
  __shared__ __align__(16) ushort Vt[64 * 64];
  const int chunk = blockIdx.x;
  const int seq = blockIdx.y;
  const int b = seq >> 4, h = seq & 15;
  const int tid = threadIdx.x;
  const size_t base = ((size_t)b * 2048 + chunk * 64) * 1024 + h * 64;

#pragma unroll
  for (int r = 0; r < 2; ++r) {
    const int idx = tid + (r << 8);       // 0..511
    const int j = idx >> 3;               // 0..63
    const int e0 = (idx & 7) << 3;        // 0,8,..,56
    const bf16x8_t kv8 = *(const bf16x8_t*)(kbuf + base + (size_t)j * 1024 + e0);
    const bf16x8_t vv8 = *(const bf16x8_t*)(vbuf + base + (size_t)j * 1024 + e0);
#pragma unroll
    for (int t = 0; t < 8; ++t) {
      *(ushort*)((char*)Kt + SWB(e0 + t, j * 2)) = (ushort)kv8[t];
      *(ushort*)((char*)Vt + SWB(e0 + t, j * 2)) = (ushort)vv8[t];
    }
  }
  __syncthreads();

  if (tid < 64) {
    float s = 0.f;
#pragma unroll
    for (int g = 0; g < 8; ++g) {
      const bf16x8_t kr = *(const bf16x8_t*)((char*)Kt + SWB(tid, g * 16));
#pragma unroll
      for (int t = 0; t < 8; ++t) s += bf2f((ushort)kr[t]);
    }
    ksum[((size_t)seq * 32 + chunk) * 64 + tid] = s;
  }

  const int lane = tid & 63;
  const int wv = tid >> 6;
  const int wm = (wv >> 1) * 32;
  const int wd = (wv & 1) * 32;
  const int fr = lane & 15;
  const int khb = (lane >> 4) * 16;   // k byte offset within 64-B k-half

  f32x4_t acc[2][2];
#pragma unroll
  for (int m = 0; m < 2; ++m)
#pragma unroll
    for (int n = 0; n < 2; ++n) acc[m][n] = (f32x4_t){0.f, 0.f, 0.f, 0.f};

#pragma unroll
  for (int kk = 0; kk < 2; ++kk) {
    bf16x8_t av[2], bk[2];
#pragma unroll
    for (int m = 0; m < 2; ++m)
      av[m] = *(const bf16x8_t*)((char*)Vt + SWB(wm + m * 16 + fr, kk * 64 + khb));
#pragma unroll
    for (int n = 0; n < 2; ++n)
      bk[n] = *(const bf16x8_t*)((char*)Kt + SWB(wd + n * 16 + fr, kk * 64 + khb));
#pragma unroll
    for (int m = 0; m < 2; ++m)
#pragma unroll
      for (int n = 0; n < 2; ++n)
        acc[m][n] = __builtin_amdgcn_mfma_f32_16x16x32_bf16(
            av[m], bk[n], acc[m][n], 0, 0, 0);
  }

  const size_t kvbase = ((size_t)seq * 32 + chunk) << 12;
  const int rq = (lane >> 4) * 4;
#pragma unroll
  for (int m = 0; m < 2; ++m)
#pragma unroll
    for (int r = 0; r < 4; ++r) {
      const int mrow = wm + m * 16 + rq + r;
#pragma unroll
      for (int n = 0; n < 2; ++n) {
        const int dcol = wd + n * 16 + fr;
        kvsum[kvbase + (size_t)mrow * 64 + dcol] = acc[m][n][r];
      }
    }
}

// exclusive prefix scan over chunks; grid = 32 seq * 16 slices
__global__ __launch_bounds__(256) void scan_kernel(
    float* __restrict__ kvsum, float* __restrict__ ksum)
{
  const int slice = blockIdx.x & 15;
  const int seq = blockIdx.x >> 4;
  const int e = slice * 256 + threadIdx.x;   // 0..4095
  const size_t base = ((size_t)seq << 17) + e;
  float run = 0.f;
  for (int c = 0; c < 32; ++c) {
    const size_t idx = base + ((size_t)c << 12);
    const float t = kvsum[idx];
    kvsum[idx] = run;
    run += t;
  }
  if (slice == 0 && threadIdx.x < 64) {
    const size_t kb = (size_t)seq * 2048 + threadIdx.x;
    float run2 = 0.f;
    for (int c = 0; c < 32; ++c) {
      const float t = ksum[kb + (size_t)c * 64];
      ksum[kb + (size_t)c * 64] = run2;
      run2 += t;
    }
  }
}

// Per (seq, chunk): S = QK^T (causal-masked) -> P bf16; O = P*V + Q*KVp;
// z_i = q_i . kcum_excl + sum_{j<=i} S_ij; out = O / z, written bf16.
__global__ __launch_bounds__(256) void attn_chunk_kernel(
    const ushort* __restrict__ qbuf, const ushort* __restrict__ kbuf,
    const ushort* __restrict__ vbuf, const float* __restrict__ kvsum,
    const float* __restrict__ ksum, ushort* __restrict__ attn)
{
  __shared__ __align__(16) ushort Qs[64 * 64];
  __shared__ __align__(16) ushort Ks[64 * 64];   // reused as KVp bf16
  __shared__ __align__(16) ushort Vt[64 * 64];
  __shared__ __align__(16) ushort Pl[64 * 64];
  __shared__ float ksp[64];
  __shared__ float zinv[64];
  const int chunk = blockIdx.x;
  const int seq = blockIdx.y;
  const int b = seq >> 4, h = seq & 15;
  const int tid = threadIdx.x;
  const size_t base = ((size_t)b * 2048 + chunk * 64) * 1024 + h * 64;

  // ---- stage Q, K straight (swizzled); V transposed ----
#pragma unroll
  for (int r = 0; r < 2; ++r) {
    const int idx = tid + (r << 8);
    const int row = idx >> 3;             // 0..63
    const int e0 = (idx & 7) << 3;        // element offset 0..56
    const int kb = e0 << 1;               // byte offset
    *(bf16x8_t*)((char*)Qs + SWB(row, kb)) =
        *(const bf16x8_t*)(qbuf + base + (size_t)row * 1024 + e0);
    *(bf16x8_t*)((char*)Ks + SWB(row, kb)) =
        *(const bf16x8_t*)(kbuf + base + (size_t)row * 1024 + e0);
    const bf16x8_t vv8 = *(const bf16x8_t*)(vbuf + base + (size_t)row * 1024 + e0);
#pragma unroll
    for (int t = 0; t < 8; ++t)
      *(ushort*)((char*)Vt + SWB(e0 + t, row * 2)) = (ushort)vv8[t];
  }
  if (tid < 64) ksp[tid] = ksum[((size_t)seq * 32 + chunk) * 64 + tid];
  __syncthreads();

  const int lane = tid & 63;
  const int wv = tid >> 6;
  const int wr = (wv >> 1) * 32;   // output row quadrant
  const int wc = (wv & 1) * 32;    // output col quadrant
  const int fr = lane & 15;
  const int khb = (lane >> 4) * 16;
  const int rq = (lane >> 4) * 4;

  // ---- S = Q K^T ----
  f32x4_t sf[2][2];
#pragma unroll
  for (int m = 0; m < 2; ++m)
#pragma unroll
    for (int n = 0; n < 2; ++n) sf[m][n] = (f32x4_t){0.f, 0.f, 0.f, 0.f};
#pragma unroll
  for (int kk = 0; kk < 2; ++kk) {
    bf16x8_t aq[2], bk[2];
#pragma unroll
    for (int m = 0; m < 2; ++m)
      aq[m] = *(const bf16x8_t*)((char*)Qs + SWB(wr + m * 16 + fr, kk * 64 + khb));
#pragma unroll
    for (int n = 0; n < 2; ++n)
      bk[n] = *(const bf16x8_t*)((char*)Ks + SWB(wc + n * 16 + fr, kk * 64 + khb));
#pragma unroll
    for (int m = 0; m < 2; ++m)
#pragma unroll
      for (int n = 0; n < 2; ++n)
        sf[m][n] = __builtin_amdgcn_mfma_f32_16x16x32_bf16(
            aq[m], bk[n], sf[m][n], 0, 0, 0);
  }
  __syncthreads();   // all S-frag LDS reads done; Ks reusable

  // ---- mask + write P (bf16); stage KVp (fp32 global -> bf16 LDS) ----
#pragma unroll
  for (int m = 0; m < 2; ++m)
#pragma unroll
    for (int r = 0; r < 4; ++r) {
      const int i = wr + m * 16 + rq + r;
#pragma unroll
      for (int n = 0; n < 2; ++n) {
        const int j = wc + n * 16 + fr;
        const float pv = (j <= i) ? sf[m][n][r] : 0.f;
        *(ushort*)((char*)Pl + SWB(i, j * 2)) = f2bf(pv);
      }
    }
  const size_t kvbase = ((size_t)seq * 32 + chunk) << 12;
#pragma unroll
  for (int r = 0; r < 2; ++r) {
    const int idx = tid + (r << 8);
    const int mrow = idx >> 3;
    const int d0 = (idx & 7) << 3;
    const float4 lo = *(const float4*)(kvsum + kvbase + (size_t)mrow * 64 + d0);
    const float4 hi = *(const float4*)(kvsum + kvbase + (size_t)mrow * 64 + d0 + 4);
    bf16x8_t kv8;
    kv8[0] = (short)f2bf(lo.x); kv8[1] = (short)f2bf(lo.y);
    kv8[2] = (short)f2bf(lo.z); kv8[3] = (short)f2bf(lo.w);
    kv8[4] = (short)f2bf(hi.x); kv8[5] = (short)f2bf(hi.y);
    kv8[6] = (short)f2bf(hi.z); kv8[7] = (short)f2bf(hi.w);
    *(bf16x8_t*)((char*)Ks + SWB(mrow, d0 << 1)) = kv8;
  }
  __syncthreads();

  // ---- z on first 64 threads ----
  if (tid < 64) {
    const int i = tid;
    float dsum = 0.f, ssum = 0.f;
#pragma unroll
    for (int g = 0; g < 8; ++g) {
      const bf16x8_t qr = *(const bf16x8_t*)((char*)Qs + SWB(i, g * 16));
      const bf16x8_t pr = *(const bf16x8_t*)((char*)Pl + SWB(i, g * 16));
#pragma unroll
      for (int t = 0; t < 8; ++t) {
        dsum = fmaf(bf2f((ushort)qr[t]), ksp[g * 8 + t], dsum);
        ssum += bf2f((ushort)pr[t]);
      }
    }
    zinv[i] = 1.f / (dsum + ssum + EPSF);
  }

  // ---- O = P*V + Q*KVp ----
  f32x4_t of[2][2];
#pragma unroll
  for (int m = 0; m < 2; ++m)
#pragma unroll
    for (int n = 0; n < 2; ++n) of[m][n] = (f32x4_t){0.f, 0.f, 0.f, 0.f};
#pragma unroll
  for (int kk = 0; kk < 2; ++kk) {
    bf16x8_t ap[2], bv[2];
#pragma unroll
    for (int m = 0; m < 2; ++m)
      ap[m] = *(const bf16x8_t*)((char*)Pl + SWB(wr + m * 16 + fr, kk * 64 + khb));
#pragma unroll
    for (int n = 0; n < 2; ++n)
      bv[n] = *(const bf16x8_t*)((char*)Vt + SWB(wc + n * 16 + fr, kk * 64 + khb));
#pragma unroll
    for (int m = 0; m < 2; ++m)
#pragma unroll
      for (int n = 0; n < 2; ++n)
        of[m][n] = __builtin_amdgcn_mfma_f32_16x16x32_bf16(
            ap[m], bv[n], of[m][n], 0, 0, 0);
  }
#pragma unroll
  for (int kk = 0; kk < 2; ++kk) {
    bf16x8_t aq[2], bkv[2];
#pragma unroll
    for (int m = 0; m < 2; ++m)
      aq[m] = *(const bf16x8_t*)((char*)Qs + SWB(wr + m * 16 + fr, kk * 64 + khb));
#pragma unroll
    for (int n = 0; n < 2; ++n)
      bkv[n] = *(const bf16x8_t*)((char*)Ks + SWB(wc + n * 16 + fr, kk * 64 + khb));
#pragma unroll
    for (int m = 0; m < 2; ++m)
#pragma unroll
      for (int n = 0; n < 2; ++n)
        of[m][n] = __builtin_amdgcn_mfma_f32_16x16x32_bf16(
            aq[m], bkv[n], of[m][n], 0, 0, 0);
  }
  __syncthreads();   // zinv ready

  // ---- scale + write bf16 ----
#pragma unroll
  for (int m = 0; m < 2; ++m)
#pragma unroll
    for (int r = 0; r < 4; ++r) {
      const int i = wr + m * 16 + rq + r;
      const float z = zinv[i];
#pragma unroll
      for (int n = 0; n < 2; ++n) {
        const int mcol = wc + n * 16 + fr;
        attn[base + (size_t)i * 1024 + mcol] = f2bf(of[m][n][r] * z);
      }
    }
}

// ================= launch ==================================================
extern "C" void kernel_launch(void* const* d_in, const int* in_sizes, int n_in,
                              void* d_out, int out_size, void* d_ws, size_t ws_size,
                              hipStream_t stream)
{
  (void)in_sizes; (void)n_in; (void)out_size; (void)ws_size;
  const float* x  = (const float*)d_in[0];
  const float* Wq = (const float*)d_in[1];
  const float* Wk = (const float*)d_in[2];
  const float* Wv = (const float*)d_in[3];
  const float* Wo = (const float*)d_in[4];
  float* out = (float*)d_out;

  const size_t NM = (size_t)4096 * 1024;
  ushort* xb  = (ushort*)d_ws;          // bf16, NM
  ushort* wqb = xb + NM;                // bf16, 1M each
  ushort* wkb = wqb + (1 << 20);
  ushort* wvb = wkb + (1 << 20);
  ushort* wob = wvb + (1 << 20);
  ushort* qb  = wob + (1 << 20);        // bf16 q/k/v, NM each
  ushort* kb  = qb + NM;
  ushort* vb  = kb + NM;
  ushort* at  = vb + NM;                // bf16 attn out, NM
  float*  ksm = (float*)(at + NM);      // fp32, 65536
  float*  kvs = (float*)d_out;          // reuse d_out as kvsum scratch (NM floats)

  cvt5_kernel<<<8192, 256, 0, stream>>>(
      (const float4*)x, (const float4*)Wq, (const float4*)Wk,
      (const float4*)Wv, (const float4*)Wo,
      (ushort4*)xb, (ushort4*)wqb, (ushort4*)wkb, (ushort4*)wvb, (ushort4*)wob);
  qkv_gemm_kernel<<<dim3(32, 24), 256, 0, stream>>>(xb, wqb, wkb, wvb, qb, kb, vb);
  chunk_sums_kernel<<<dim3(32, 32), 256, 0, stream>>>(kb, vb, kvs, ksm);
  scan_kernel<<<512, 256, 0, stream>>>(kvs, ksm);
  attn_chunk_kernel<<<dim3(32, 32), 256, 0, stream>>>(qb, kb, vb, kvs, ksm, at);
  out_gemm_kernel<<<dim3(32, 8), 256, 0, stream>>>(at, wob, out);
}